// Round 6
// baseline (214.142 us; speedup 1.0000x reference)
//
#include <hip/hip_runtime.h>
#include <math.h>

// Problem constants
#define B_   128
#define I_   2048
#define F_   8
#define J_   16
#define D_   16
#define JD   256
#define IT   16            // i per block
#define NIT  (I_/IT)       // 128
#define BT   16            // b per block
#define NBT  (B_/BT)       // 8
#define VROW 260           // padded vlds row stride (dwords)

typedef _Float16 f16;
typedef _Float16 f16x8 __attribute__((ext_vector_type(8)));
typedef _Float16 f16x4 __attribute__((ext_vector_type(4)));
typedef float    f32x4 __attribute__((ext_vector_type(4)));

#if defined(__has_builtin)
#  if __has_builtin(__builtin_amdgcn_permlane32_swap)
#    define HAVE_PLS32 1
#  endif
#endif

// 16-lane DPP sum (squash kernels)
template <int CTRL>
__device__ __forceinline__ float dpp_add(float v) {
    int t = __builtin_amdgcn_update_dpp(0, __float_as_int(v), CTRL, 0xF, 0xF, true);
    return v + __int_as_float(t);
}
__device__ __forceinline__ float row_sum16(float v) {
    v = dpp_add<0x128>(v);
    v = dpp_add<0x124>(v);
    v = dpp_add<0x122>(v);
    v = dpp_add<0x121>(v);
    return v;
}

// quarter-sum for MFMA C-layout: add lane^16 (ds_swizzle) then lane^32.
__device__ __forceinline__ float fold16(float p) {
    return p + __int_as_float(__builtin_amdgcn_ds_swizzle(__float_as_int(p), 0x401F));
}
__device__ __forceinline__ float fold32(float p) {
#ifdef HAVE_PLS32
    auto r = __builtin_amdgcn_permlane32_swap(__float_as_int(p), __float_as_int(p),
                                              false, false);
    return __int_as_float(r[0]) + __int_as_float(r[1]);
#else
    return p + __shfl_xor(p, 32);
#endif
}

// Hardware f32 global atomic add (no return). hipcc's atomicAdd(float*) may
// lower to a CAS loop without -munsafe-fp-atomics; emit the instruction.
__device__ __forceinline__ void atomic_add_f32(float* p, float v) {
#if defined(__AMDGCN__)
    asm volatile("global_atomic_add_f32 %0, %1, off" :: "v"(p), "v"(v) : "memory");
#else
    atomicAdd(p, v);
#endif
}

// ---------------------------------------------------------------------------
// f32 -> f16 conversion of W then x. 4 elems/thread.
// ---------------------------------------------------------------------------
__global__ __launch_bounds__(256) void cvt_f16(const float* __restrict__ W,
                                               const float* __restrict__ x,
                                               f16* __restrict__ Wt,
                                               f16* __restrict__ xt) {
    const size_t NW = (size_t)J_ * I_ * D_ * F_;
    const size_t NX = (size_t)B_ * I_ * F_;
    size_t k = ((size_t)blockIdx.x * 256 + threadIdx.x) * 4;
    if (k < NW) {
        float4 a = *reinterpret_cast<const float4*>(W + k);
        f16x4 h = {(f16)a.x, (f16)a.y, (f16)a.z, (f16)a.w};
        *reinterpret_cast<f16x4*>(Wt + k) = h;
    } else {
        size_t k2 = k - NW;
        if (k2 < NX) {
            float4 a = *reinterpret_cast<const float4*>(x + k2);
            f16x4 h = {(f16)a.x, (f16)a.y, (f16)a.z, (f16)a.w};
            *reinterpret_cast<f16x4*>(xt + k2) = h;
        }
    }
}

// ---------------------------------------------------------------------------
// Pass kernel (MFMA + atomic accumulate + inline squash of previous pass).
// Block = (i-tile 16) x (b-tile 16), 4 waves <-> 4 j each. Lane: lb=l&15,
// lq=l>>4.
// PASS==0: c = 1/16 uniform, vsum unused.
// PASS==1: vsum = squash(vS0) computed inline (16 KB per-block read from L2).
// PASS==2: vsum = squash(vS0) + squash(vS1).
// Phase A: per (j,il): u[d,b] = mfma(W~, x~) (K=8 of 32); logit = sum_d v*u
//   via 4 FMA + fold16 + fold32; lanes<16 write cl.
// Softmax over j per (b,i) thread. Phase C: s-GEMM, K=(i16,f8)=128, B-frag
//   c*x~ in-register. Epilogue: 16 hardware f32 atomics into vSo[B][JD].
// ---------------------------------------------------------------------------
template <int PASS>
__global__ __launch_bounds__(256) void caps_pass(
    const f16* __restrict__ Wt,     // [J][I][D][F]
    const f16* __restrict__ xt,     // [B][I][F]
    const float* __restrict__ vS0,  // [B][JD] s-accumulator of pass 0 (PASS>=1)
    const float* __restrict__ vS1,  // [B][JD] s-accumulator of pass 1 (PASS==2)
    float* __restrict__ vSo)        // [B][JD] this pass's s-accumulator
{
    const int it = blockIdx.x, bg = blockIdx.y;
    const int i0 = it * IT, b0 = bg * BT;
    const int t = threadIdx.x;
    const int w = t >> 6, l = t & 63;
    const int lb = l & 15, lq = l >> 4;

    __shared__ f16   xlds[IT][BT][F_];                  // 4 KB
    __shared__ float cl[PASS ? (J_ * IT * BT) : 1];     // 16 KB (PASS>=1)
    __shared__ float vlds[PASS ? (BT * VROW) : 1];      // 16.6 KB (PASS>=1)

    // stage x~ tile: thread (b = t>>4, i = t&15) loads 8 f16 (16B) coalesced
    {
        const int b = t >> 4, i = t & 15;
        f16x8 v = *reinterpret_cast<const f16x8*>(
            xt + ((size_t)(b0 + b) * I_ + i0 + i) * F_);
        *reinterpret_cast<f16x8*>(&xlds[i][b][0]) = v;
    }

    // inline squash of previous accumulator(s): thread (b = t>>4, j = t&15)
    if constexpr (PASS >= 1) {
        const int b = t >> 4, j = t & 15;
        const float* p0 = vS0 + (size_t)(b0 + b) * JD + j * D_;
        float s[16], v[16];
        #pragma unroll
        for (int q = 0; q < 4; ++q) {
            float4 a = *reinterpret_cast<const float4*>(p0 + q * 4);
            s[q * 4 + 0] = a.x; s[q * 4 + 1] = a.y;
            s[q * 4 + 2] = a.z; s[q * 4 + 3] = a.w;
        }
        float sq = 0.f;
        #pragma unroll
        for (int d = 0; d < 16; ++d) sq = fmaf(s[d], s[d], sq);
        float scale = sq / (1.f + sq) * rsqrtf(sq + 1e-7f);
        #pragma unroll
        for (int d = 0; d < 16; ++d) v[d] = scale * s[d];
        if constexpr (PASS == 2) {
            const float* p1 = vS1 + (size_t)(b0 + b) * JD + j * D_;
            #pragma unroll
            for (int q = 0; q < 4; ++q) {
                float4 a = *reinterpret_cast<const float4*>(p1 + q * 4);
                s[q * 4 + 0] = a.x; s[q * 4 + 1] = a.y;
                s[q * 4 + 2] = a.z; s[q * 4 + 3] = a.w;
            }
            sq = 0.f;
            #pragma unroll
            for (int d = 0; d < 16; ++d) sq = fmaf(s[d], s[d], sq);
            scale = sq / (1.f + sq) * rsqrtf(sq + 1e-7f);
            #pragma unroll
            for (int d = 0; d < 16; ++d) v[d] += scale * s[d];
        }
        #pragma unroll
        for (int q = 0; q < 4; ++q) {
            float4 a = {v[q * 4 + 0], v[q * 4 + 1], v[q * 4 + 2], v[q * 4 + 3]};
            *reinterpret_cast<float4*>(&vlds[b * VROW + j * D_ + q * 4]) = a;
        }
    }
    __syncthreads();

    // per-j W~ base pointers (row d = lb, f contiguous)
    const f16* wp[4];
    #pragma unroll
    for (int jj = 0; jj < 4; ++jj)
        wp[jj] = Wt + (((size_t)(w * 4 + jj) * I_ + i0) * D_ + lb) * F_;

    f32x4 zero = {0.f, 0.f, 0.f, 0.f};
    f32x4 sacc[4] = {zero, zero, zero, zero};

    if constexpr (PASS >= 1) {
        // v fragments from LDS: vr[jj] = vsum[b0+lb][j][lq*4 .. +3]
        float4 vr[4];
        #pragma unroll
        for (int jj = 0; jj < 4; ++jj)
            vr[jj] = *reinterpret_cast<const float4*>(
                &vlds[lb * VROW + (w * 4 + jj) * D_ + lq * 4]);

        // ---- Phase A: logits ----
        #pragma unroll 4
        for (int il = 0; il < IT; ++il) {
            f16x8 bf = {0, 0, 0, 0, 0, 0, 0, 0};
            if (l < 16) bf = *reinterpret_cast<const f16x8*>(&xlds[il][lb][0]);
            #pragma unroll
            for (int jj = 0; jj < 4; ++jj) {
                f16x8 af = *reinterpret_cast<const f16x8*>(wp[jj] + il * (D_ * F_));
                f32x4 u = __builtin_amdgcn_mfma_f32_16x16x32_f16(af, bf, zero, 0, 0, 0);
                float p = u[0] * vr[jj].x + u[1] * vr[jj].y +
                          u[2] * vr[jj].z + u[3] * vr[jj].w;
                p = fold32(fold16(p));
                if (l < 16) cl[(((w * 4 + jj) * IT) + il) * BT + lb] = p;
            }
        }
        __syncthreads();

        // ---- softmax over j: thread (i = t>>4, b = t&15) ----
        {
            const int i = t >> 4, b = t & 15;
            float e[J_];
            float mx = -1e30f;
            #pragma unroll
            for (int j = 0; j < J_; ++j) {
                e[j] = cl[(j * IT + i) * BT + b];
                mx = fmaxf(mx, e[j]);
            }
            float ssum = 0.f;
            #pragma unroll
            for (int j = 0; j < J_; ++j) { e[j] = __expf(e[j] - mx); ssum += e[j]; }
            const float inv = 1.f / ssum;
            #pragma unroll
            for (int j = 0; j < J_; ++j) cl[(j * IT + i) * BT + b] = e[j] * inv;
        }
        __syncthreads();
    }

    // ---- Phase C: s-GEMM, K = (i,f) = 128 -> 4 MFMAs per j ----
    #pragma unroll
    for (int m = 0; m < 4; ++m) {
        const int i = m * 4 + lq;
        f16x8 xf = *reinterpret_cast<const f16x8*>(&xlds[i][lb][0]);
        #pragma unroll
        for (int jj = 0; jj < 4; ++jj) {
            f16x8 bf;
            if constexpr (PASS >= 1) {
                const float cf = cl[(((w * 4 + jj) * IT) + i) * BT + lb];
                const f16 ch = (f16)cf;
                bf = xf * ch;           // 4x v_pk_mul_f16
            } else {
                bf = xf;
            }
            f16x8 af = *reinterpret_cast<const f16x8*>(wp[jj] + i * (D_ * F_));
            sacc[jj] = __builtin_amdgcn_mfma_f32_16x16x32_f16(af, bf, sacc[jj], 0, 0, 0);
        }
    }

    // ---- epilogue: accumulate into vSo with hardware f32 atomics ----
    #pragma unroll
    for (int jj = 0; jj < 4; ++jj) {
        if constexpr (PASS == 0) sacc[jj] *= 0.0625f;
        float* base = vSo + (size_t)(b0 + lb) * JD + (w * 4 + jj) * D_ + lq * 4;
        #pragma unroll
        for (int r = 0; r < 4; ++r)
            atomic_add_f32(base + r, sacc[jj][r]);
    }
}

// ---------------------------------------------------------------------------
// Final squash: out = squash(vS2). Grid B_, 256 threads (t = jd).
// ---------------------------------------------------------------------------
__global__ __launch_bounds__(256) void sq_out(const float* __restrict__ vS2,
                                              float* __restrict__ out) {
    const int b = blockIdx.x;
    const int t = threadIdx.x;
    const float s = vS2[(size_t)b * JD + t];
    const float sq = row_sum16(s * s);
    const float scale = sq / (1.f + sq) * rsqrtf(sq + 1e-7f);
    out[(size_t)b * JD + t] = scale * s;
}

extern "C" void kernel_launch(void* const* d_in, const int* in_sizes, int n_in,
                              void* d_out, int out_size, void* d_ws,
                              size_t ws_size, hipStream_t stream) {
    const float* x = (const float*)d_in[0];   // [128, 2048, 8]
    const float* W = (const float*)d_in[1];   // [16, 2048, 16, 8]
    float* out = (float*)d_out;               // [128, 16, 16]

    // Workspace: Wt f16 | xt f16 | vS0 f32 | vS1 f32 | vS2 f32 (contiguous)
    f16* Wt = (f16*)d_ws;
    f16* xt = Wt + (size_t)J_ * I_ * D_ * F_;        // +4,194,304 f16
    float* vS0 = (float*)(xt + (size_t)B_ * I_ * F_); // +2,097,152 f16
    float* vS1 = vS0 + (size_t)B_ * JD;
    float* vS2 = vS1 + (size_t)B_ * JD;

    // zero the three s-accumulators (one graph-captured memset node)
    hipMemsetAsync(vS0, 0, 3 * (size_t)B_ * JD * sizeof(float), stream);

    const int TOT4 = (int)(((size_t)J_ * I_ * D_ * F_ + (size_t)B_ * I_ * F_) / 4);
    cvt_f16<<<TOT4 / 256, 256, 0, stream>>>(W, x, Wt, xt);

    dim3 grid(NIT, NBT), blk(256);

    // r=0: uniform c -> vS0
    caps_pass<0><<<grid, blk, 0, stream>>>(Wt, xt, nullptr, nullptr, vS0);
    // r=1: vsum = squash(vS0) inline -> vS1
    caps_pass<1><<<grid, blk, 0, stream>>>(Wt, xt, vS0, nullptr, vS1);
    // r=2: vsum = squash(vS0)+squash(vS1) inline -> vS2
    caps_pass<2><<<grid, blk, 0, stream>>>(Wt, xt, vS0, vS1, vS2);
    // out = squash(vS2)
    sq_out<<<B_, 256, 0, stream>>>(vS2, out);
}

// Round 7
// 81.587 us; speedup vs baseline: 2.6247x; 2.6247x over previous
//
#include <hip/hip_runtime.h>
#include <math.h>

// Problem constants
#define B_   128
#define I_   2048
#define F_   8
#define J_   16
#define D_   16
#define JD   256
#define BT   16            // b per block
#define NBT  (B_/BT)       // 8
#define SROW 257           // padded slds row stride (dwords)

typedef _Float16 f16;
typedef _Float16 f16x8 __attribute__((ext_vector_type(8)));
typedef _Float16 f16x4 __attribute__((ext_vector_type(4)));
typedef float    f32x4 __attribute__((ext_vector_type(4)));

#if defined(__has_builtin)
#  if __has_builtin(__builtin_amdgcn_permlane32_swap)
#    define HAVE_PLS32 1
#  endif
#endif

// 16-lane DPP sum — pure VALU
template <int CTRL>
__device__ __forceinline__ float dpp_add(float v) {
    int t = __builtin_amdgcn_update_dpp(0, __float_as_int(v), CTRL, 0xF, 0xF, true);
    return v + __int_as_float(t);
}
__device__ __forceinline__ float row_sum16(float v) {
    v = dpp_add<0x128>(v);
    v = dpp_add<0x124>(v);
    v = dpp_add<0x122>(v);
    v = dpp_add<0x121>(v);
    return v;
}

// quarter-sum for MFMA C-layout: add lane^16 (ds_swizzle) then lane^32.
__device__ __forceinline__ float fold16(float p) {
    return p + __int_as_float(__builtin_amdgcn_ds_swizzle(__float_as_int(p), 0x401F));
}
__device__ __forceinline__ float fold32(float p) {
#ifdef HAVE_PLS32
    auto r = __builtin_amdgcn_permlane32_swap(__float_as_int(p), __float_as_int(p),
                                              false, false);
    return __int_as_float(r[0]) + __int_as_float(r[1]);
#else
    return p + __shfl_xor(p, 32);
#endif
}

// ---------------------------------------------------------------------------
// f32 -> f16 conversion of W then x. 4 elems/thread.
// ---------------------------------------------------------------------------
__global__ __launch_bounds__(256) void cvt_f16(const float* __restrict__ W,
                                               const float* __restrict__ x,
                                               f16* __restrict__ Wt,
                                               f16* __restrict__ xt) {
    const size_t NW = (size_t)J_ * I_ * D_ * F_;
    const size_t NX = (size_t)B_ * I_ * F_;
    size_t k = ((size_t)blockIdx.x * 256 + threadIdx.x) * 4;
    if (k < NW) {
        float4 a = *reinterpret_cast<const float4*>(W + k);
        f16x4 h = {(f16)a.x, (f16)a.y, (f16)a.z, (f16)a.w};
        *reinterpret_cast<f16x4*>(Wt + k) = h;
    } else {
        size_t k2 = k - NW;
        if (k2 < NX) {
            float4 a = *reinterpret_cast<const float4*>(x + k2);
            f16x4 h = {(f16)a.x, (f16)a.y, (f16)a.z, (f16)a.w};
            *reinterpret_cast<f16x4*>(xt + k2) = h;
        }
    }
}

// ---------------------------------------------------------------------------
// Pass kernel (MFMA, streaming). Block = (i-tile IT) x (b-tile 16), 4 waves
// <-> 4 j each. Lane: lb=l&15 (b or d), lq=l>>4.
// Phase A (PASS=1): per (j,il): u[d,b] = mfma(W~[d,f], x~[f,b]) (K=8 of 32);
//   logit = sum_d v*u via 4 FMA + fold16 + fold32; lanes<16 write cl.
// Softmax over j per (b,i) thread. Phase C: s-GEMM, K=(i,f)=IT*8, B-frag
//   c*x~ in-register. Epilogue: LDS transpose (slds, UNIONed with cl — needs
//   a barrier after phase C) -> coalesced f16 store to sp[it][b][jd].
// ---------------------------------------------------------------------------
template <int IT, int PASS>
__global__ __launch_bounds__(256) void caps_pass(
    const f16* __restrict__ Wt,     // [J][I][D][F]
    const f16* __restrict__ xt,     // [B][I][F]
    const float* __restrict__ vsum, // [B][JD] (PASS==1)
    f16* __restrict__ sp)           // [I_/IT][B][JD]
{
    const int it = blockIdx.x, bg = blockIdx.y;
    const int i0 = it * IT, b0 = bg * BT;
    const int t = threadIdx.x;
    const int w = t >> 6, l = t & 63;
    const int lb = l & 15, lq = l >> 4;

    __shared__ f16 xlds[IT][BT][F_];               // 2 or 4 KB
    __shared__ union {
        float cl[J_ * IT * BT];                    // softmax coeffs (PASS=1)
        float slds[BT * SROW];                     // epilogue transpose
    } sh;                                          // 16.4 KB

    // stage x~ tile
    if constexpr (IT == 16) {
        const int b = t >> 4, i = t & 15;
        f16x8 v = *reinterpret_cast<const f16x8*>(
            xt + ((size_t)(b0 + b) * I_ + i0 + i) * F_);
        *reinterpret_cast<f16x8*>(&xlds[i][b][0]) = v;
    } else {
        if (t < 128) {
            const int b = t >> 3, i = t & 7;
            f16x8 v = *reinterpret_cast<const f16x8*>(
                xt + ((size_t)(b0 + b) * I_ + i0 + i) * F_);
            *reinterpret_cast<f16x8*>(&xlds[i][b][0]) = v;
        }
    }

    // per-j W~ base pointers (row d = lb, f contiguous)
    const f16* wp[4];
    #pragma unroll
    for (int jj = 0; jj < 4; ++jj)
        wp[jj] = Wt + (((size_t)(w * 4 + jj) * I_ + i0) * D_ + lb) * F_;

    f32x4 zero = {0.f, 0.f, 0.f, 0.f};
    f32x4 sacc[4] = {zero, zero, zero, zero};

    if constexpr (PASS == 1) {
        // v fragments: vr[jj] = vsum[b0+lb][j][lq*4 .. +3]
        float4 vr[4];
        #pragma unroll
        for (int jj = 0; jj < 4; ++jj)
            vr[jj] = *reinterpret_cast<const float4*>(
                vsum + (size_t)(b0 + lb) * JD + (w * 4 + jj) * D_ + lq * 4);
        __syncthreads();

        // ---- Phase A: logits ----
        #pragma unroll 4
        for (int il = 0; il < IT; ++il) {
            f16x8 bf = {0, 0, 0, 0, 0, 0, 0, 0};
            if (l < 16) bf = *reinterpret_cast<const f16x8*>(&xlds[il][lb][0]);
            #pragma unroll
            for (int jj = 0; jj < 4; ++jj) {
                f16x8 af = *reinterpret_cast<const f16x8*>(wp[jj] + il * (D_ * F_));
                f32x4 u = __builtin_amdgcn_mfma_f32_16x16x32_f16(af, bf, zero, 0, 0, 0);
                float p = u[0] * vr[jj].x + u[1] * vr[jj].y +
                          u[2] * vr[jj].z + u[3] * vr[jj].w;
                p = fold32(fold16(p));
                if (l < 16) sh.cl[(((w * 4 + jj) * IT) + il) * BT + lb] = p;
            }
        }
        __syncthreads();

        // ---- softmax over j: thread (i, b) ----
        if (t < IT * BT) {
            const int i = t >> 4, b = t & 15;
            float e[J_];
            float mx = -1e30f;
            #pragma unroll
            for (int j = 0; j < J_; ++j) {
                e[j] = sh.cl[(j * IT + i) * BT + b];
                mx = fmaxf(mx, e[j]);
            }
            float ssum = 0.f;
            #pragma unroll
            for (int j = 0; j < J_; ++j) { e[j] = __expf(e[j] - mx); ssum += e[j]; }
            const float inv = 1.f / ssum;
            #pragma unroll
            for (int j = 0; j < J_; ++j) sh.cl[(j * IT + i) * BT + b] = e[j] * inv;
        }
        __syncthreads();
    } else {
        __syncthreads();
    }

    // ---- Phase C: s-GEMM, K = (i,f) = IT*8 -> IT/4 MFMAs per j ----
    #pragma unroll
    for (int m = 0; m < IT / 4; ++m) {
        const int i = m * 4 + lq;
        f16x8 xf = *reinterpret_cast<const f16x8*>(&xlds[i][lb][0]);
        #pragma unroll
        for (int jj = 0; jj < 4; ++jj) {
            f16x8 bf;
            if constexpr (PASS == 1) {
                const float cf = sh.cl[(((w * 4 + jj) * IT) + i) * BT + lb];
                const f16 ch = (f16)cf;
                bf = xf * ch;           // v_pk_mul_f16
            } else {
                bf = xf;
            }
            f16x8 af = *reinterpret_cast<const f16x8*>(wp[jj] + i * (D_ * F_));
            sacc[jj] = __builtin_amdgcn_mfma_f32_16x16x32_f16(af, bf, sacc[jj], 0, 0, 0);
        }
    }

    // slds aliases cl: all phase-C cl reads must complete first
    __syncthreads();

    // ---- epilogue: transpose via LDS (padded rows), coalesced f16 store ----
    #pragma unroll
    for (int jj = 0; jj < 4; ++jj) {
        if constexpr (PASS == 0) sacc[jj] *= 0.0625f;
        const int j = w * 4 + jj;
        #pragma unroll
        for (int r = 0; r < 4; ++r)
            sh.slds[lb * SROW + j * D_ + lq * 4 + r] = sacc[jj][r];
    }
    __syncthreads();
    {
        const int b = t >> 4, seg = t & 15;
        float o[16];
        #pragma unroll
        for (int k = 0; k < 16; ++k)
            o[k] = sh.slds[b * SROW + seg * 16 + k];
        f16x8 o0 = {(f16)o[0], (f16)o[1], (f16)o[2],  (f16)o[3],
                    (f16)o[4], (f16)o[5], (f16)o[6],  (f16)o[7]};
        f16x8 o1 = {(f16)o[8], (f16)o[9], (f16)o[10], (f16)o[11],
                    (f16)o[12], (f16)o[13], (f16)o[14], (f16)o[15]};
        f16* dst = sp + ((size_t)it * B_ + b0 + b) * JD + seg * 16;
        *reinterpret_cast<f16x8*>(dst) = o0;
        *reinterpret_cast<f16x8*>(dst + 8) = o1;
    }
}

// ---------------------------------------------------------------------------
// Reduce over i-tiles + squash. Grid (B, 2 j-halves), 512 threads.
// Stage 1: thread (g = t>>4, c8 = t&15) sums NITT/32 i-tiles with f16x8
// loads. Stage 2: t<128 sums the 32 g-partials from LDS, DPP-squash, store.
// MODE 0: vA = squash(s); MODE 1: vB = vA + squash(s); MODE 2: out = squash(s)
// ---------------------------------------------------------------------------
template <int NITT, int MODE>
__global__ __launch_bounds__(512) void caps_reduce(
    const f16* __restrict__ sp,    // [NITT][B][JD] f16
    const float* __restrict__ vA,  // [B][JD] (MODE==1)
    float* __restrict__ vout)      // [B][JD]
{
    const int b = blockIdx.x, jh = blockIdx.y;
    const int t = threadIdx.x;
    const int g = t >> 4, c8 = t & 15;
    constexpr int ITS = NITT / 32;

    float acc[8] = {0.f, 0.f, 0.f, 0.f, 0.f, 0.f, 0.f, 0.f};
    const f16* base = sp + ((size_t)(g * ITS) * B_ + b) * JD + jh * 128 + c8 * 8;
    #pragma unroll
    for (int k = 0; k < ITS; ++k) {
        f16x8 v = *reinterpret_cast<const f16x8*>(base + (size_t)k * B_ * JD);
        #pragma unroll
        for (int e = 0; e < 8; ++e) acc[e] += (float)v[e];
    }

    __shared__ float lds[32][128];
    #pragma unroll
    for (int e = 0; e < 8; ++e) lds[g][c8 * 8 + e] = acc[e];
    __syncthreads();

    if (t < 128) {
        float a = 0.f;
        #pragma unroll
        for (int gg = 0; gg < 32; ++gg) a += lds[gg][t];
        const float sq = row_sum16(a * a);
        const float scale = sq / (1.f + sq) * rsqrtf(sq + 1e-7f);
        float v = scale * a;
        const int jd = jh * 128 + t;
        if (MODE == 1) v += vA[(size_t)b * JD + jd];
        vout[(size_t)b * JD + jd] = v;
    }
}

extern "C" void kernel_launch(void* const* d_in, const int* in_sizes, int n_in,
                              void* d_out, int out_size, void* d_ws,
                              size_t ws_size, hipStream_t stream) {
    const float* x = (const float*)d_in[0];   // [128, 2048, 8]
    const float* W = (const float*)d_in[1];   // [16, 2048, 16, 8]
    float* out = (float*)d_out;               // [128, 16, 16]

    const size_t NW = (size_t)J_ * I_ * D_ * F_;   // 4,194,304
    const size_t NX = (size_t)B_ * I_ * F_;        // 2,097,152

    f16* Wt = (f16*)d_ws;
    f16* xt = Wt + NW;
    f16* sp = xt + NX;

    const int TOT4 = (int)((NW + NX) / 4);

    // IT=8 path needs sp[256][B][JD] f16 = 16.8 MB; fall back to IT=16 if ws
    // is tight (deterministic in ws_size -> graph-safe).
    const size_t need8 = NW * 2 + NX * 2 +
                         (size_t)256 * B_ * JD * 2 + 2 * (size_t)B_ * JD * 4;
    dim3 rgrid(B_, 2), rblk(512);

    if (ws_size >= need8) {
        float* vA = (float*)(sp + (size_t)256 * B_ * JD);
        float* vB = vA + (size_t)B_ * JD;
        dim3 grid(I_ / 8, NBT), blk(256);
        cvt_f16<<<TOT4 / 256, 256, 0, stream>>>(W, x, Wt, xt);
        caps_pass<8, 0><<<grid, blk, 0, stream>>>(Wt, xt, nullptr, sp);
        caps_reduce<256, 0><<<rgrid, rblk, 0, stream>>>(sp, nullptr, vA);
        caps_pass<8, 1><<<grid, blk, 0, stream>>>(Wt, xt, vA, sp);
        caps_reduce<256, 1><<<rgrid, rblk, 0, stream>>>(sp, vA, vB);
        caps_pass<8, 1><<<grid, blk, 0, stream>>>(Wt, xt, vB, sp);
        caps_reduce<256, 2><<<rgrid, rblk, 0, stream>>>(sp, nullptr, out);
    } else {
        float* vA = (float*)(sp + (size_t)128 * B_ * JD);
        float* vB = vA + (size_t)B_ * JD;
        dim3 grid(I_ / 16, NBT), blk(256);
        cvt_f16<<<TOT4 / 256, 256, 0, stream>>>(W, x, Wt, xt);
        caps_pass<16, 0><<<grid, blk, 0, stream>>>(Wt, xt, nullptr, sp);
        caps_reduce<128, 0><<<rgrid, rblk, 0, stream>>>(sp, nullptr, vA);
        caps_pass<16, 1><<<grid, blk, 0, stream>>>(Wt, xt, vA, sp);
        caps_reduce<128, 1><<<rgrid, rblk, 0, stream>>>(sp, vA, vB);
        caps_pass<16, 1><<<grid, blk, 0, stream>>>(Wt, xt, vB, sp);
        caps_reduce<128, 2><<<rgrid, rblk, 0, stream>>>(sp, nullptr, out);
    }
}